// Round 4
// baseline (1924.109 us; speedup 1.0000x reference)
//
#include <hip/hip_runtime.h>
#include <hip/hip_bf16.h>

#define EPSN 1e-12f
#define NB   1024            // dst buckets
#define RB   256             // rows per bucket (N / NB)
#define CHK  4096            // edges per scatter workgroup

__device__ __forceinline__ float rdlane(float v, int k) {
    return __int_as_float(__builtin_amdgcn_readlane(__float_as_int(v), k));
}
__device__ __forceinline__ float preluf(float x, float a) {
    return x >= 0.0f ? x : a * x;
}

// ---------------- K1: in_feat = feat_z @ weight  (+ anchor output branch) ---
__global__ __launch_bounds__(256) void k_transform(
    const float* __restrict__ feat, const float* __restrict__ weight,
    const float* __restrict__ bias, const float* __restrict__ prelu_a,
    float* __restrict__ in_feat, float* __restrict__ out_anchor,
    int N, int totalWaves)
{
    const int lane = threadIdx.x & 63;
    const int wid = (int)((blockIdx.x * (size_t)blockDim.x + threadIdx.x) >> 6);

    float wreg[128];
    #pragma unroll
    for (int k = 0; k < 128; ++k) wreg[k] = weight[k * 64 + lane];
    const float bj = bias[lane];
    const float a  = prelu_a[0];

    for (int row = wid; row < N; row += totalWaves) {
        const float* rp = feat + (size_t)row * 128;
        float r0 = rp[lane];
        float r1 = rp[64 + lane];
        float acc0 = 0.0f, acc1 = 0.0f;
        #pragma unroll
        for (int k = 0; k < 64; ++k) {
            acc0 = fmaf(rdlane(r0, k), wreg[k],      acc0);
            acc1 = fmaf(rdlane(r1, k), wreg[64 + k], acc1);
        }
        float acc = acc0 + acc1;

        if ((row & 3) == 0) {
            float y = preluf(acc + bj, a);
            float s = y * y;
            #pragma unroll
            for (int off = 32; off >= 1; off >>= 1) s += __shfl_xor(s, off, 64);
            float dn = fmaxf(sqrtf(s), EPSN);
            out_anchor[(size_t)(row >> 2) * 64 + lane] = y / dn;
            in_feat[(size_t)row * 64 + lane] = 0.0f;
        } else {
            in_feat[(size_t)row * 64 + lane] = acc;
        }
    }
}

// ---------------- S1: bucket counts --------------------------------------
__global__ __launch_bounds__(256) void s_count(
    const int* __restrict__ edst, int E, unsigned* __restrict__ cnt)
{
    __shared__ unsigned hist[NB];
    for (int i = threadIdx.x; i < NB; i += 256) hist[i] = 0;
    __syncthreads();
    const int base = blockIdx.x * CHK;
    #pragma unroll
    for (int i = 0; i < 16; ++i) {
        int idx = base + i * 256 + threadIdx.x;
        if (idx < E) atomicAdd(&hist[((unsigned)edst[idx]) >> 8], 1u);
    }
    __syncthreads();
    for (int i = threadIdx.x; i < NB; i += 256) {
        unsigned c = hist[i];
        if (c) atomicAdd(&cnt[i], c);
    }
}

// ---------------- S2: exclusive scan over NB counts (one block) -----------
__global__ __launch_bounds__(1024) void s_scan(
    const unsigned* __restrict__ cnt,
    unsigned* __restrict__ basep, unsigned* __restrict__ cur)
{
    __shared__ unsigned sc[NB];
    const int t = threadIdx.x;
    unsigned my = cnt[t];
    sc[t] = my;
    __syncthreads();
    for (int off = 1; off < NB; off <<= 1) {
        unsigned a = (t >= off) ? sc[t - off] : 0u;
        __syncthreads();
        sc[t] += a;
        __syncthreads();
    }
    unsigned excl = sc[t] - my;
    basep[t] = excl;
    cur[t]   = excl;
    if (t == NB - 1) basep[NB] = sc[t];
}

// ---------------- S3: scatter edges into bucket-sorted record array -------
// record: x = src (bits 0..17) | dst_local (bits 18..25), y = bits(w)
__global__ __launch_bounds__(256) void s_scatter(
    const int* __restrict__ esrc, const int* __restrict__ edst,
    const float* __restrict__ ew, int E,
    unsigned* __restrict__ cur, uint2* __restrict__ recs)
{
    __shared__ unsigned hist[NB];
    for (int i = threadIdx.x; i < NB; i += 256) hist[i] = 0;
    __syncthreads();
    const int base = blockIdx.x * CHK;
    int d[16];
    #pragma unroll
    for (int i = 0; i < 16; ++i) {
        int idx = base + i * 256 + threadIdx.x;
        d[i] = (idx < E) ? edst[idx] : -1;
        if (d[i] >= 0) atomicAdd(&hist[((unsigned)d[i]) >> 8], 1u);
    }
    __syncthreads();
    // claim contiguous global ranges; hist[b] becomes the write cursor
    for (int i = threadIdx.x; i < NB; i += 256) {
        unsigned c = hist[i];
        hist[i] = c ? atomicAdd(&cur[i], c) : 0u;
    }
    __syncthreads();
    #pragma unroll
    for (int i = 0; i < 16; ++i) {
        int idx = base + i * 256 + threadIdx.x;
        if (d[i] >= 0) {
            unsigned b = ((unsigned)d[i]) >> 8;
            unsigned slot = atomicAdd(&hist[b], 1u);
            unsigned pack = ((unsigned)esrc[idx]) | ((((unsigned)d[i]) & 255u) << 18);
            recs[slot] = make_uint2(pack, __float_as_uint(ew[idx]));
        }
    }
}

// ---------------- S4: per-bucket LDS accumulation (no global atomics) -----
__global__ __launch_bounds__(1024) void s_accum(
    const float* __restrict__ in_feat, const uint2* __restrict__ recs,
    const unsigned* __restrict__ basep, float* __restrict__ h)
{
    __shared__ float hs[RB * 64];   // 64 KB
    const int lane = threadIdx.x & 63;
    const int wave = threadIdx.x >> 6;           // 0..15
    for (int i = threadIdx.x; i < RB * 64; i += 1024) hs[i] = 0.0f;
    __syncthreads();

    const int b = blockIdx.x;
    const int start = (int)basep[b], end = (int)basep[b + 1];
    const int stride = 16;

    int idx = start + wave;
    while (idx + 7 * stride < end) {
        uint2 r[8]; float v[8];
        #pragma unroll
        for (int j = 0; j < 8; ++j) r[j] = recs[idx + j * stride];
        #pragma unroll
        for (int j = 0; j < 8; ++j)
            v[j] = in_feat[((size_t)(r[j].x & 0x3FFFFu) << 6) + lane];
        #pragma unroll
        for (int j = 0; j < 8; ++j)
            atomicAdd(&hs[(r[j].x >> 18) * 64 + lane], v[j] * __uint_as_float(r[j].y));
        idx += 8 * stride;
    }
    for (; idx < end; idx += stride) {
        uint2 r = recs[idx];
        float v = in_feat[((size_t)(r.x & 0x3FFFFu) << 6) + lane];
        atomicAdd(&hs[(r.x >> 18) * 64 + lane], v * __uint_as_float(r.y));
    }
    __syncthreads();
    const size_t hbase = (size_t)b * (RB * 64);
    for (int i = threadIdx.x; i < RB * 64; i += 1024) h[hbase + i] = hs[i];
}

// ---------------- fallback K2 (atomic scatter) ----------------------------
#define K2_U 8
__global__ __launch_bounds__(256) void k_edges(
    const float* __restrict__ in_feat, const int* __restrict__ esrc,
    const int* __restrict__ edst, const float* __restrict__ ew,
    float* __restrict__ h, int E, int totalWaves)
{
    const int lane = threadIdx.x & 63;
    int wid = (int)((blockIdx.x * (size_t)blockDim.x + threadIdx.x) >> 6);
    wid = __builtin_amdgcn_readfirstlane(wid);
    const int chunk = (E + totalWaves - 1) / totalWaves;
    int e0 = wid * chunk;
    int e1 = min(e0 + chunk, E);
    for (int base = e0; base < e1; base += K2_U) {
        const int nb = min(K2_U, e1 - base);
        int s[K2_U], d[K2_U]; float w[K2_U];
        #pragma unroll
        for (int j = 0; j < K2_U; ++j) {
            int idx = base + ((j < nb) ? j : 0);
            s[j] = esrc[idx]; d[j] = edst[idx]; w[j] = ew[idx];
        }
        float v[K2_U];
        #pragma unroll
        for (int j = 0; j < K2_U; ++j)
            v[j] = in_feat[((size_t)s[j] << 6) + lane];
        #pragma unroll
        for (int j = 0; j < K2_U; ++j)
            if (j < nb) atomicAdd(h + ((size_t)d[j] << 6) + lane, v[j] * w[j]);
    }
}

// ---------------- K3: activation + pool + two GEMVs + l2norm --------------
__global__ __launch_bounds__(256) void k_finalize(
    const float* __restrict__ h, const float* __restrict__ bias,
    const float* __restrict__ prelu_a,
    const float* __restrict__ w_sub, const float* __restrict__ b_sub,
    const float* __restrict__ w_gcn, const float* __restrict__ b_gcn,
    float* __restrict__ out_sub, float* __restrict__ out_gcn,
    int G, int totalWaves)
{
    const int lane = threadIdx.x & 63;
    const int wid = (int)((blockIdx.x * (size_t)blockDim.x + threadIdx.x) >> 6);

    float wsreg[64], wgreg[64];
    #pragma unroll
    for (int k = 0; k < 64; ++k) wsreg[k] = w_sub[lane * 64 + k];
    #pragma unroll
    for (int k = 0; k < 64; ++k) wgreg[k] = w_gcn[lane * 64 + k];
    const float bj  = bias[lane];
    const float bsj = b_sub[lane];
    const float bgj = b_gcn[lane];
    const float a   = prelu_a[0];

    for (int g = wid; g < G; g += totalWaves) {
        const float* hp = h + (size_t)g * 256;
        float p0 = preluf(hp[lane]       + bj, a);
        float p1 = preluf(hp[64  + lane] + bj, a);
        float p2 = preluf(hp[128 + lane] + bj, a);
        float p3 = preluf(hp[192 + lane] + bj, a);
        float pool = (p0 + p1 + p2 + p3) * 0.25f;
        float gcn  = p0;

        float as = bsj, ag = bgj;
        #pragma unroll
        for (int k = 0; k < 64; ++k) {
            as = fmaf(rdlane(pool, k), wsreg[k], as);
            ag = fmaf(rdlane(gcn,  k), wgreg[k], ag);
        }
        float ss = as * as, sg = ag * ag;
        #pragma unroll
        for (int off = 32; off >= 1; off >>= 1) {
            ss += __shfl_xor(ss, off, 64);
            sg += __shfl_xor(sg, off, 64);
        }
        out_sub[(size_t)g * 64 + lane] = as / fmaxf(sqrtf(ss), EPSN);
        out_gcn[(size_t)g * 64 + lane] = ag / fmaxf(sqrtf(sg), EPSN);
    }
}

extern "C" void kernel_launch(void* const* d_in, const int* in_sizes, int n_in,
                              void* d_out, int out_size, void* d_ws, size_t ws_size,
                              hipStream_t stream)
{
    const float* feat    = (const float*)d_in[0];
    const int*   esrc    = (const int*)  d_in[1];
    const int*   edst    = (const int*)  d_in[2];
    const float* ew      = (const float*)d_in[3];
    const float* weight  = (const float*)d_in[4];
    const float* bias    = (const float*)d_in[5];
    const float* prelu_a = (const float*)d_in[6];
    const float* w_sub   = (const float*)d_in[7];
    const float* b_sub   = (const float*)d_in[8];
    const float* w_gcn   = (const float*)d_in[9];
    const float* b_gcn   = (const float*)d_in[10];

    const int N = in_sizes[0] / 128;
    const int E = in_sizes[1];
    const int G = N / 4;

    // ws layout
    char* wsb = (char*)d_ws;
    float*    in_feat = (float*)wsb;                                   // N*64 f32
    float*    h       = (float*)(wsb + (size_t)N * 64 * 4);            // N*64 f32
    uint2*    recs    = (uint2*)(wsb + (size_t)2 * N * 64 * 4);        // E * 8B
    unsigned* cnt     = (unsigned*)(wsb + (size_t)2 * N * 64 * 4 + (size_t)E * 8);
    unsigned* basep   = cnt + NB;
    unsigned* cur     = basep + NB + 1;
    const size_t ws_need = (size_t)2 * N * 64 * 4 + (size_t)E * 8 + (NB * 3 + 16) * 4;

    float* out        = (float*)d_out;
    float* out_sub    = out;
    float* out_anchor = out + (size_t)G * 64;
    float* out_gcn    = out + (size_t)2 * G * 64;

    const bool sorted_path = (N == NB * RB) && (ws_size >= ws_need);

    {   // K1
        const int blocks = 2048, tw = blocks * 4;
        k_transform<<<blocks, 256, 0, stream>>>(feat, weight, bias, prelu_a,
                                                in_feat, out_anchor, N, tw);
    }

    if (sorted_path) {
        hipMemsetAsync(cnt, 0, NB * sizeof(unsigned), stream);
        const int nwg = (E + CHK - 1) / CHK;
        s_count  <<<nwg, 256, 0, stream>>>(edst, E, cnt);
        s_scan   <<<1, 1024, 0, stream>>>(cnt, basep, cur);
        s_scatter<<<nwg, 256, 0, stream>>>(esrc, edst, ew, E, cur, recs);
        s_accum  <<<NB, 1024, 0, stream>>>(in_feat, recs, basep, h);
    } else {
        hipMemsetAsync(h, 0, (size_t)N * 64 * sizeof(float), stream);
        const int blocks = 2048, tw = blocks * 4;
        k_edges<<<blocks, 256, 0, stream>>>(in_feat, esrc, edst, ew, h, E, tw);
    }

    {   // K3
        const int blocks = 4096, tw = blocks * 4;
        k_finalize<<<blocks, 256, 0, stream>>>(h, bias, prelu_a, w_sub, b_sub,
                                               w_gcn, b_gcn, out_sub, out_gcn, G, tw);
    }
}

// Round 5
// 783.577 us; speedup vs baseline: 2.4555x; 2.4555x over previous
//
#include <hip/hip_runtime.h>
#include <hip/hip_bf16.h>

#define EPSN 1e-12f
#define NB   1024            // coarse dst buckets (dst >> 8)
#define RB   256             // rows per coarse bucket (N / NB)
#define CHK  4096            // edges per count/scatter workgroup

__device__ __forceinline__ float rdlane(float v, int k) {
    return __int_as_float(__builtin_amdgcn_readlane(__float_as_int(v), k));
}
__device__ __forceinline__ float preluf(float x, float a) {
    return x >= 0.0f ? x : a * x;
}

// ---------------- K1: in_feat = feat_z @ weight  (+ anchor output branch) ---
__global__ __launch_bounds__(256) void k_transform(
    const float* __restrict__ feat, const float* __restrict__ weight,
    const float* __restrict__ bias, const float* __restrict__ prelu_a,
    float* __restrict__ in_feat, float* __restrict__ out_anchor,
    int N, int totalWaves)
{
    const int lane = threadIdx.x & 63;
    const int wid = (int)((blockIdx.x * (size_t)blockDim.x + threadIdx.x) >> 6);

    float wreg[128];
    #pragma unroll
    for (int k = 0; k < 128; ++k) wreg[k] = weight[k * 64 + lane];
    const float bj = bias[lane];
    const float a  = prelu_a[0];

    for (int row = wid; row < N; row += totalWaves) {
        const float* rp = feat + (size_t)row * 128;
        float r0 = rp[lane];
        float r1 = rp[64 + lane];
        float acc0 = 0.0f, acc1 = 0.0f;
        #pragma unroll
        for (int k = 0; k < 64; ++k) {
            acc0 = fmaf(rdlane(r0, k), wreg[k],      acc0);
            acc1 = fmaf(rdlane(r1, k), wreg[64 + k], acc1);
        }
        float acc = acc0 + acc1;

        if ((row & 3) == 0) {
            float y = preluf(acc + bj, a);
            float s = y * y;
            #pragma unroll
            for (int off = 32; off >= 1; off >>= 1) s += __shfl_xor(s, off, 64);
            float dn = fmaxf(sqrtf(s), EPSN);
            out_anchor[(size_t)(row >> 2) * 64 + lane] = y / dn;
            in_feat[(size_t)row * 64 + lane] = 0.0f;
        } else {
            in_feat[(size_t)row * 64 + lane] = acc;
        }
    }
}

// ---------------- S1: coarse bucket counts --------------------------------
__global__ __launch_bounds__(256) void s_count(
    const int* __restrict__ edst, int E, unsigned* __restrict__ cnt)
{
    __shared__ unsigned hist[NB];
    for (int i = threadIdx.x; i < NB; i += 256) hist[i] = 0;
    __syncthreads();
    const int base = blockIdx.x * CHK;
    #pragma unroll
    for (int i = 0; i < 16; ++i) {
        int idx = base + i * 256 + threadIdx.x;
        if (idx < E) atomicAdd(&hist[((unsigned)edst[idx]) >> 8], 1u);
    }
    __syncthreads();
    for (int i = threadIdx.x; i < NB; i += 256) {
        unsigned c = hist[i];
        if (c) atomicAdd(&cnt[i], c);
    }
}

// ---------------- S2: exclusive scan over NB counts (one block) -----------
__global__ __launch_bounds__(1024) void s_scan(
    const unsigned* __restrict__ cnt,
    unsigned* __restrict__ basep, unsigned* __restrict__ cur)
{
    __shared__ unsigned sc[NB];
    const int t = threadIdx.x;
    unsigned my = cnt[t];
    sc[t] = my;
    __syncthreads();
    for (int off = 1; off < NB; off <<= 1) {
        unsigned a = (t >= off) ? sc[t - off] : 0u;
        __syncthreads();
        sc[t] += a;
        __syncthreads();
    }
    unsigned excl = sc[t] - my;
    basep[t] = excl;
    cur[t]   = excl;
    if (t == NB - 1) basep[NB] = sc[t];
}

// ---------------- S3: scatter edges into coarse-bucket-sorted records -----
// record: x = src (bits 0..17) | dst_local (bits 18..25), y = bits(w)
__global__ __launch_bounds__(256) void s_scatter(
    const int* __restrict__ esrc, const int* __restrict__ edst,
    const float* __restrict__ ew, int E,
    unsigned* __restrict__ cur, uint2* __restrict__ recs)
{
    __shared__ unsigned hist[NB];
    for (int i = threadIdx.x; i < NB; i += 256) hist[i] = 0;
    __syncthreads();
    const int base = blockIdx.x * CHK;
    int d[16];
    #pragma unroll
    for (int i = 0; i < 16; ++i) {
        int idx = base + i * 256 + threadIdx.x;
        d[i] = (idx < E) ? edst[idx] : -1;
        if (d[i] >= 0) atomicAdd(&hist[((unsigned)d[i]) >> 8], 1u);
    }
    __syncthreads();
    for (int i = threadIdx.x; i < NB; i += 256) {
        unsigned c = hist[i];
        hist[i] = c ? atomicAdd(&cur[i], c) : 0u;
    }
    __syncthreads();
    #pragma unroll
    for (int i = 0; i < 16; ++i) {
        int idx = base + i * 256 + threadIdx.x;
        if (d[i] >= 0) {
            unsigned b = ((unsigned)d[i]) >> 8;
            unsigned slot = atomicAdd(&hist[b], 1u);
            unsigned pack = ((unsigned)esrc[idx]) | ((((unsigned)d[i]) & 255u) << 18);
            recs[slot] = make_uint2(pack, __float_as_uint(ew[idx]));
        }
    }
}

// ---------------- S4: per-bucket fine sort (by dst_local) -----------------
// emits fully dst-sorted records {src, w_bits} + per-row offsets rs[N+1]
__global__ __launch_bounds__(256) void s_sortfine(
    const uint2* __restrict__ recs, const unsigned* __restrict__ basep,
    uint2* __restrict__ recf, unsigned* __restrict__ rs, int E)
{
    __shared__ unsigned hist[RB], sc[RB], cur[RB];
    const int t = threadIdx.x;
    const int b = blockIdx.x;
    const unsigned start = basep[b], end = basep[b + 1];
    hist[t] = 0;
    __syncthreads();
    for (unsigned i = start + t; i < end; i += 256)
        atomicAdd(&hist[recs[i].x >> 18], 1u);
    __syncthreads();
    sc[t] = hist[t];
    __syncthreads();
    for (int off = 1; off < RB; off <<= 1) {
        unsigned v = (t >= off) ? sc[t - off] : 0u;
        __syncthreads();
        sc[t] += v;
        __syncthreads();
    }
    const unsigned excl = sc[t] - hist[t];
    cur[t] = start + excl;
    rs[b * RB + t] = start + excl;
    if (b == 0 && t == 0) rs[NB * RB] = (unsigned)E;
    __syncthreads();
    for (unsigned i = start + t; i < end; i += 256) {
        uint2 r = recs[i];
        unsigned slot = atomicAdd(&cur[r.x >> 18], 1u);
        recf[slot] = make_uint2(r.x & 0x3FFFFu, r.y);
    }
}

// ---------------- S5: one wave per dst row, register accumulation ---------
// no atomics, no LDS; 8 gathers in flight per wave.
__global__ __launch_bounds__(256) void s_accum3(
    const float* __restrict__ in_feat, const uint2* __restrict__ recf,
    const unsigned* __restrict__ rs, float* __restrict__ h,
    int NROWS, int totalWaves)
{
    const int lane = threadIdx.x & 63;
    const int wid = (int)((blockIdx.x * (size_t)blockDim.x + threadIdx.x) >> 6);

    for (int row = wid; row < NROWS; row += totalWaves) {
        const unsigned s = rs[row], e = rs[row + 1];
        float acc = 0.0f;
        unsigned done = s;
        while (done < e) {
            const int c = (int)min(64u, e - done);
            uint2 rcd = make_uint2(0u, 0u);
            if (lane < c) rcd = recf[done + lane];   // coalesced 8B x c
            for (int j0 = 0; j0 < c; j0 += 8) {
                float v[8], wj[8];
                #pragma unroll
                for (int jj = 0; jj < 8; ++jj) {
                    const int idx = j0 + jj;
                    const int cl  = (idx < c) ? idx : (c - 1);
                    const unsigned sidx =
                        (unsigned)__builtin_amdgcn_readlane((int)rcd.x, cl);
                    const float wv =
                        __int_as_float(__builtin_amdgcn_readlane((int)rcd.y, cl));
                    v[jj]  = in_feat[((size_t)sidx << 6) + lane];
                    wj[jj] = (idx < c) ? wv : 0.0f;
                }
                #pragma unroll
                for (int jj = 0; jj < 8; ++jj) acc = fmaf(v[jj], wj[jj], acc);
            }
            done += (unsigned)c;
        }
        h[((size_t)row << 6) + lane] = acc;
    }
}

// ---------------- fallback K2 (atomic scatter) ----------------------------
#define K2_U 8
__global__ __launch_bounds__(256) void k_edges(
    const float* __restrict__ in_feat, const int* __restrict__ esrc,
    const int* __restrict__ edst, const float* __restrict__ ew,
    float* __restrict__ h, int E, int totalWaves)
{
    const int lane = threadIdx.x & 63;
    int wid = (int)((blockIdx.x * (size_t)blockDim.x + threadIdx.x) >> 6);
    wid = __builtin_amdgcn_readfirstlane(wid);
    const int chunk = (E + totalWaves - 1) / totalWaves;
    int e0 = wid * chunk;
    int e1 = min(e0 + chunk, E);
    for (int base = e0; base < e1; base += K2_U) {
        const int nb = min(K2_U, e1 - base);
        int s[K2_U], d[K2_U]; float w[K2_U];
        #pragma unroll
        for (int j = 0; j < K2_U; ++j) {
            int idx = base + ((j < nb) ? j : 0);
            s[j] = esrc[idx]; d[j] = edst[idx]; w[j] = ew[idx];
        }
        float v[K2_U];
        #pragma unroll
        for (int j = 0; j < K2_U; ++j)
            v[j] = in_feat[((size_t)s[j] << 6) + lane];
        #pragma unroll
        for (int j = 0; j < K2_U; ++j)
            if (j < nb) atomicAdd(h + ((size_t)d[j] << 6) + lane, v[j] * w[j]);
    }
}

// ---------------- K3: activation + pool + two GEMVs + l2norm --------------
__global__ __launch_bounds__(256) void k_finalize(
    const float* __restrict__ h, const float* __restrict__ bias,
    const float* __restrict__ prelu_a,
    const float* __restrict__ w_sub, const float* __restrict__ b_sub,
    const float* __restrict__ w_gcn, const float* __restrict__ b_gcn,
    float* __restrict__ out_sub, float* __restrict__ out_gcn,
    int G, int totalWaves)
{
    const int lane = threadIdx.x & 63;
    const int wid = (int)((blockIdx.x * (size_t)blockDim.x + threadIdx.x) >> 6);

    float wsreg[64], wgreg[64];
    #pragma unroll
    for (int k = 0; k < 64; ++k) wsreg[k] = w_sub[lane * 64 + k];
    #pragma unroll
    for (int k = 0; k < 64; ++k) wgreg[k] = w_gcn[lane * 64 + k];
    const float bj  = bias[lane];
    const float bsj = b_sub[lane];
    const float bgj = b_gcn[lane];
    const float a   = prelu_a[0];

    for (int g = wid; g < G; g += totalWaves) {
        const float* hp = h + (size_t)g * 256;
        float p0 = preluf(hp[lane]       + bj, a);
        float p1 = preluf(hp[64  + lane] + bj, a);
        float p2 = preluf(hp[128 + lane] + bj, a);
        float p3 = preluf(hp[192 + lane] + bj, a);
        float pool = (p0 + p1 + p2 + p3) * 0.25f;
        float gcn  = p0;

        float as = bsj, ag = bgj;
        #pragma unroll
        for (int k = 0; k < 64; ++k) {
            as = fmaf(rdlane(pool, k), wsreg[k], as);
            ag = fmaf(rdlane(gcn,  k), wgreg[k], ag);
        }
        float ss = as * as, sg = ag * ag;
        #pragma unroll
        for (int off = 32; off >= 1; off >>= 1) {
            ss += __shfl_xor(ss, off, 64);
            sg += __shfl_xor(sg, off, 64);
        }
        out_sub[(size_t)g * 64 + lane] = as / fmaxf(sqrtf(ss), EPSN);
        out_gcn[(size_t)g * 64 + lane] = ag / fmaxf(sqrtf(sg), EPSN);
    }
}

extern "C" void kernel_launch(void* const* d_in, const int* in_sizes, int n_in,
                              void* d_out, int out_size, void* d_ws, size_t ws_size,
                              hipStream_t stream)
{
    const float* feat    = (const float*)d_in[0];
    const int*   esrc    = (const int*)  d_in[1];
    const int*   edst    = (const int*)  d_in[2];
    const float* ew      = (const float*)d_in[3];
    const float* weight  = (const float*)d_in[4];
    const float* bias    = (const float*)d_in[5];
    const float* prelu_a = (const float*)d_in[6];
    const float* w_sub   = (const float*)d_in[7];
    const float* b_sub   = (const float*)d_in[8];
    const float* w_gcn   = (const float*)d_in[9];
    const float* b_gcn   = (const float*)d_in[10];

    const int N = in_sizes[0] / 128;
    const int E = in_sizes[1];
    const int G = N / 4;

    // ws layout:
    //   [0, 67.1MB)      in_feat
    //   [67.1, 134.2MB)  region A: recs_coarse during sort, then h (overlay;
    //                    recs_coarse is dead before s_accum3 writes h)
    //   [134.2, 167.8MB) recfine
    //   tail             cnt/basep/cur
    char* wsb = (char*)d_ws;
    float*    in_feat = (float*)wsb;
    float*    regA    = (float*)(wsb + (size_t)N * 64 * 4);
    uint2*    recs    = (uint2*)regA;            // coarse records (dead after s_sortfine)
    float*    h       = regA;                    // h overlays coarse records
    uint2*    recf    = (uint2*)(wsb + (size_t)2 * N * 64 * 4);
    unsigned* cnt     = (unsigned*)(wsb + (size_t)2 * N * 64 * 4 + (size_t)E * 8);
    unsigned* basep   = cnt + NB;
    unsigned* cur     = basep + NB + 1;
    const size_t ws_need = (size_t)2 * N * 64 * 4 + (size_t)E * 8 + (NB * 3 + 16) * 4;

    float* out        = (float*)d_out;
    float* out_sub    = out;
    float* out_anchor = out + (size_t)G * 64;
    float* out_gcn    = out + (size_t)2 * G * 64;

    // rs (N+1 row offsets, 1.05MB) parked in out_sub's region: written by
    // s_sortfine, read by s_accum3, then fully overwritten by k_finalize.
    unsigned* rs = (unsigned*)d_out;

    const bool sorted_path = (N == NB * RB) && (ws_size >= ws_need);

    {   // K1
        const int blocks = 2048, tw = blocks * 4;
        k_transform<<<blocks, 256, 0, stream>>>(feat, weight, bias, prelu_a,
                                                in_feat, out_anchor, N, tw);
    }

    if (sorted_path) {
        hipMemsetAsync(cnt, 0, NB * sizeof(unsigned), stream);
        const int nwg = (E + CHK - 1) / CHK;
        s_count   <<<nwg, 256, 0, stream>>>(edst, E, cnt);
        s_scan    <<<1, 1024, 0, stream>>>(cnt, basep, cur);
        s_scatter <<<nwg, 256, 0, stream>>>(esrc, edst, ew, E, cur, recs);
        s_sortfine<<<NB, 256, 0, stream>>>(recs, basep, recf, rs, E);
        {
            const int blocks = 2048, tw = blocks * 4;   // 8192 waves, 32 rows each
            s_accum3<<<blocks, 256, 0, stream>>>(in_feat, recf, rs, h, N, tw);
        }
    } else {
        hipMemsetAsync(h, 0, (size_t)N * 64 * sizeof(float), stream);
        const int blocks = 2048, tw = blocks * 4;
        k_edges<<<blocks, 256, 0, stream>>>(in_feat, esrc, edst, ew, h, E, tw);
    }

    {   // K3
        const int blocks = 4096, tw = blocks * 4;
        k_finalize<<<blocks, 256, 0, stream>>>(h, bias, prelu_a, w_sub, b_sub,
                                               w_gcn, b_gcn, out_sub, out_gcn, G, tw);
    }
}